// Round 2
// baseline (114.411 us; speedup 1.0000x reference)
//
#include <hip/hip_runtime.h>

typedef short bf16x8 __attribute__((ext_vector_type(8)));
typedef float f32x4 __attribute__((ext_vector_type(4)));

#define KDIM 256
#define BT 256
#define TILE_SH (256 * 64)  // shorts per LDS tile buffer (32 KiB)

__device__ __forceinline__ unsigned short f2bf(float f) {
  unsigned u = __float_as_uint(f);
  unsigned r = (u + 0x7fffu + ((u >> 16) & 1u)) >> 16;  // RNE
  return (unsigned short)r;
}
__device__ __forceinline__ float bf2f(unsigned short b) {
  return __uint_as_float(((unsigned)b) << 16);
}

__device__ __forceinline__ void async_cp16(const void* g, void* l) {
  __builtin_amdgcn_global_load_lds(
      (const __attribute__((address_space(1))) unsigned int*)g,
      (__attribute__((address_space(3))) unsigned int*)l, 16, 0, 0);
}

// Kernel 1: fp32 -> bf16 convert, row sq (of bf16-rounded vals), column sums,
// sum(sq). 256 blocks x 32 rows. Also zeroes d_out (replaces prep2's zero).
__global__ __launch_bounds__(256) void mmd_stage(
    const float* __restrict__ src, const float* __restrict__ tgt, int ns,
    unsigned short* __restrict__ Tbf, float* __restrict__ sq,
    float* __restrict__ scol, float* __restrict__ sum_sq,
    float* __restrict__ out) {
  __shared__ float sp[256];
  __shared__ float rw[4];
  int t = threadIdx.x;
  if (blockIdx.x == 0 && t == 0) out[0] = 0.f;  // main runs after us (stream)
  int lane = t & 63, wave = t >> 6;
  sp[t] = 0.f;
  __syncthreads();
  int sub = t & 31;   // 8-elem group within row
  int rsel = t >> 5;  // row within 8-row group
  float colacc[8];
#pragma unroll
  for (int j = 0; j < 8; ++j) colacc[j] = 0.f;
  float tsq = 0.f;
#pragma unroll
  for (int it = 0; it < 4; ++it) {
    int r = blockIdx.x * 32 + it * 8 + rsel;
    const float* rp = (r < ns) ? (src + (size_t)r * KDIM)
                               : (tgt + (size_t)(r - ns) * KDIM);
    float4 v0 = *(const float4*)(rp + sub * 8);
    float4 v1 = *(const float4*)(rp + sub * 8 + 4);
    float vals[8] = {v0.x, v0.y, v0.z, v0.w, v1.x, v1.y, v1.z, v1.w};
    unsigned pk[4];
    float ssp = 0.f;
#pragma unroll
    for (int j = 0; j < 4; ++j) {
      unsigned short b0 = f2bf(vals[2 * j]);
      unsigned short b1 = f2bf(vals[2 * j + 1]);
      float x0 = bf2f(b0), x1 = bf2f(b1);
      pk[j] = (unsigned)b0 | ((unsigned)b1 << 16);
      ssp += x0 * x0 + x1 * x1;
      colacc[2 * j] += x0;
      colacc[2 * j + 1] += x1;
    }
    *(uint4*)(Tbf + (size_t)r * KDIM + sub * 8) =
        make_uint4(pk[0], pk[1], pk[2], pk[3]);
    tsq += ssp;
    float ss = ssp;
#pragma unroll
    for (int off = 16; off; off >>= 1) ss += __shfl_down(ss, off, 32);
    if (sub == 0) sq[r] = ss;
  }
#pragma unroll
  for (int j = 0; j < 8; ++j) atomicAdd(&sp[sub * 8 + j], colacc[j]);
#pragma unroll
  for (int off = 32; off; off >>= 1) tsq += __shfl_down(tsq, off, 64);
  if (lane == 0) rw[wave] = tsq;
  __syncthreads();
  atomicAdd(&scol[t], sp[t]);
  if (t == 0) atomicAdd(sum_sq, rw[0] + rw[1] + rw[2] + rw[3]);
}

__device__ __forceinline__ float2 pk_add(float2 a, float2 b) {
  return make_float2(a.x + b.x, a.y + b.y);
}
__device__ __forceinline__ float2 pk_mul(float2 a, float2 b) {
  return make_float2(a.x * b.x, a.y * b.y);
}
__device__ __forceinline__ float2 pk_fma(float2 a, float2 b, float2 c) {
  return make_float2(__builtin_fmaf(a.x, b.x, c.x),
                     __builtin_fmaf(a.y, b.y, c.y));
}

#define BAR() __builtin_amdgcn_s_barrier()
#define LGKM0() asm volatile("s_waitcnt lgkmcnt(0)" ::: "memory")
#define VMC8() asm volatile("s_waitcnt vmcnt(8)" ::: "memory")
#define VMC0() asm volatile("s_waitcnt vmcnt(0)" ::: "memory")

// Kernel 2: fused Gram-tile (MFMA) + L2 + 5-kernel sum + reduction.
// 256x256 lower-triangular tiles, 8 waves (2Mx4N), BK=64, double-buffered
// 128 KiB dynamic LDS, counted-vmcnt pipeline (T3+T4), XOR-swizzled staging
// (T2, rule-21: pre-swizzled global src + swizzled ds_read), setprio (T5).
//
// RACE FIX vs prev round: next-tile staging is issued ONLY at the top of a
// tile, after the previous tile's closing s_barrier. stage(tt+1) at top of
// tile tt writes buffer (tt+1)&1, whose last readers (tile tt-1) finished
// two barriers ago -> WAR is barrier-ordered across waves, not just within
// one wave's issue order. vmcnt(8) then drains exactly tile tt's 8 loads
// (tile tt+1's stay in flight); s_barrier makes tile tt globally visible.
// Per-tile: [stage next? ; vmcnt ; BAR] then 4 phases of
// {ds_read frag ; BAR ; lgkm0 ; 16 MFMA (setprio) ; BAR}.
//
// Tail balance: 512 blocks; blocks < extra(=16) take 2 tiles (dispatched
// first), rest 1 -> makespan ~2 rounds instead of 3.
// Also computes coef per block (replaces prep2): c4 = -log2e/(16*bw).
__global__ __launch_bounds__(512, 2) void mmd_main(
    const unsigned short* __restrict__ Tbf, const float* __restrict__ sq,
    const float* __restrict__ scol, const float* __restrict__ sum_sq,
    float* __restrict__ out, int n, int halfTiles, int extra, float inv) {
  extern __shared__ __align__(16) short smem[];
  short* As = smem;                // [2][256][64]
  short* Bs = smem + 2 * TILE_SH;  // [2][256][64]
  __shared__ float s_c4;
  __shared__ float red[8];

  int t = threadIdx.x;
  int lane = t & 63, w = t >> 6;  // 8 waves

  // ---- per-block coef (wave 0); its scol load is drained by its own use
  // before any staging, so vmcnt bookkeeping below stays exact ----
  if (w == 0) {
    float4 v = *(const float4*)(scol + lane * 4);
    float p = v.x * v.x + v.y * v.y + v.z * v.z + v.w * v.w;
#pragma unroll
    for (int off = 32; off; off >>= 1) p += __shfl_down(p, off, 64);
    if (lane == 0) {
      double ssq = (double)p, S = (double)sum_sq[0], nn = (double)n;
      double bwv = (2.0 * nn * S - 2.0 * ssq) / (nn * nn - nn) / 4.0;
      s_c4 = (float)(-1.4426950408889634 / (bwv * 16.0));
    }
  }

  // staging: thread t covers row (t>>3), pre-swizzled kgroup (t&7)^(row&7)
  int trow = t >> 3;              // 0..63
  int kg = (t & 7) ^ (trow & 7);  // pre-swizzled global kgroup
  int ldsb = w * 8 * 64;          // wave-uniform LDS base (shorts)

  // fragments (16x16x32 bf16): frow = lane&15, kq = lane>>4
  int wrow = (w >> 2) * 128;  // 0 / 128
  int wcol = (w & 3) * 64;    // 0,64,128,192
  int frow = lane & 15;
  int kq = lane >> 4;
  int colk0 = (kq ^ (frow & 7)) * 8;  // shorts; ks1 slot = colk0 ^ 32
  int aoff[4], boff[4];
#pragma unroll
  for (int mt = 0; mt < 4; ++mt) aoff[mt] = (wrow + mt * 16 + frow) * 64;
#pragma unroll
  for (int nt = 0; nt < 4; ++nt) boff[nt] = (wcol + nt * 16 + frow) * 64;

  int b = blockIdx.x;
  int nrep = (b < extra) ? 2 : 1;
  int id0 = (b < extra) ? b : b + extra;

  for (int rep = 0; rep < nrep; ++rep) {
    int id = id0 + rep * extra;
    int bi = (int)((sqrtf(8.f * (float)id + 1.f) - 1.f) * 0.5f);
    while ((bi + 1) * (bi + 2) / 2 <= id) ++bi;
    while (bi * (bi + 1) / 2 > id) --bi;
    int bj = id - bi * (bi + 1) / 2;
    int rowBase = bi * BT, colBase = bj * BT;

    const unsigned short* ga = Tbf + (size_t)(rowBase + trow) * KDIM + kg * 8;
    const unsigned short* gb = Tbf + (size_t)(colBase + trow) * KDIM + kg * 8;

    auto stage = [&](int tt) {
      short* Ad = As + (tt & 1) * TILE_SH;
      short* Bd = Bs + (tt & 1) * TILE_SH;
      const unsigned short* gA = ga + tt * 64;
      const unsigned short* gB = gb + tt * 64;
#pragma unroll
      for (int j = 0; j < 4; ++j) {
        async_cp16(gA + (size_t)j * 64 * KDIM, &Ad[j * 64 * 64 + ldsb]);
        async_cp16(gB + (size_t)j * 64 * KDIM, &Bd[j * 64 * 64 + ldsb]);
      }
    };

    f32x4 acc[8][4];
#pragma unroll
    for (int a = 0; a < 8; ++a)
#pragma unroll
      for (int c = 0; c < 4; ++c) {
        f32x4 z = {0.f, 0.f, 0.f, 0.f};
        acc[a][c] = z;
      }

    // prologue: tiles 0 and 1 in flight (16 outstanding)
    stage(0);
    stage(1);

#pragma unroll
    for (int tt = 0; tt < 4; ++tt) {
      // ---- tile top: stage next tile (WAR-safe: its buffer's readers
      // finished at tile tt-1's closing BAR), then drain tile tt ----
      if (tt >= 1 && tt <= 2) stage(tt + 1);
      if (tt < 3) VMC8();  // drains tile tt's 8; next tile's stay in flight
      else VMC0();
      BAR();  // tile tt's LDS now globally visible

      const short* Ab = As + (tt & 1) * TILE_SH;
      const short* Bb = Bs + (tt & 1) * TILE_SH;
      bf16x8 aL[4], aH[4], bv[4];

      // ---- P1: lower M-half, ks0 ----
#pragma unroll
      for (int mt = 0; mt < 4; ++mt)
        aL[mt] = *(const bf16x8*)&Ab[aoff[mt] + colk0];
#pragma unroll
      for (int nt = 0; nt < 4; ++nt)
        bv[nt] = *(const bf16x8*)&Bb[boff[nt] + colk0];
      BAR();
      LGKM0();
      __builtin_amdgcn_s_setprio(1);
#pragma unroll
      for (int mt = 0; mt < 4; ++mt)
#pragma unroll
        for (int nt = 0; nt < 4; ++nt)
          acc[mt][nt] = __builtin_amdgcn_mfma_f32_16x16x32_bf16(
              aL[mt], bv[nt], acc[mt][nt], 0, 0, 0);
      __builtin_amdgcn_s_setprio(0);
      BAR();

      // ---- P2: upper M-half, ks0 (reuse bv) ----
#pragma unroll
      for (int mt = 0; mt < 4; ++mt)
        aH[mt] = *(const bf16x8*)&Ab[aoff[mt] + 4096 + colk0];
      BAR();
      LGKM0();
      __builtin_amdgcn_s_setprio(1);
#pragma unroll
      for (int mt = 0; mt < 4; ++mt)
#pragma unroll
        for (int nt = 0; nt < 4; ++nt)
          acc[4 + mt][nt] = __builtin_amdgcn_mfma_f32_16x16x32_bf16(
              aH[mt], bv[nt], acc[4 + mt][nt], 0, 0, 0);
      __builtin_amdgcn_s_setprio(0);
      BAR();

      // ---- P3: lower M-half, ks1 ----
#pragma unroll
      for (int mt = 0; mt < 4; ++mt)
        aL[mt] = *(const bf16x8*)&Ab[aoff[mt] + (colk0 ^ 32)];
#pragma unroll
      for (int nt = 0; nt < 4; ++nt)
        bv[nt] = *(const bf16x8*)&Bb[boff[nt] + (colk0 ^ 32)];
      BAR();
      LGKM0();
      __builtin_amdgcn_s_setprio(1);
#pragma unroll
      for (int mt = 0; mt < 4; ++mt)
#pragma unroll
        for (int nt = 0; nt < 4; ++nt)
          acc[mt][nt] = __builtin_amdgcn_mfma_f32_16x16x32_bf16(
              aL[mt], bv[nt], acc[mt][nt], 0, 0, 0);
      __builtin_amdgcn_s_setprio(0);
      BAR();

      // ---- P4: upper M-half, ks1 ----
#pragma unroll
      for (int mt = 0; mt < 4; ++mt)
        aH[mt] = *(const bf16x8*)&Ab[aoff[mt] + 4096 + (colk0 ^ 32)];
      BAR();
      LGKM0();
      __builtin_amdgcn_s_setprio(1);
#pragma unroll
      for (int mt = 0; mt < 4; ++mt)
#pragma unroll
        for (int nt = 0; nt < 4; ++nt)
          acc[4 + mt][nt] = __builtin_amdgcn_mfma_f32_16x16x32_bf16(
              aH[mt], bv[nt], acc[4 + mt][nt], 0, 0, 0);
      __builtin_amdgcn_s_setprio(0);
      BAR();
    }

    // ---- epilogue: C/D layout col=lane&15, row=(lane>>4)*4+reg [m89] ----
    // e = exp2(c4*L2); kernels sum = e+e^2+e^4+e^8+e^16, float2-packed.
    float c4 = s_c4;
    float m2c4 = -2.f * c4;
    float2 m2v = make_float2(m2c4, m2c4);
    int ccol = lane & 15;
    int rb = (lane >> 4) * 4;
    const float* sqa = sq + rowBase;
    const float* sqb = sq + colBase;
    float ra[32];
#pragma unroll
    for (int mt = 0; mt < 8; ++mt) {
      float4 rv = *(const float4*)(sqa + wrow + mt * 16 + rb);
      ra[mt * 4 + 0] = rv.x * c4;
      ra[mt * 4 + 1] = rv.y * c4;
      ra[mt * 4 + 2] = rv.z * c4;
      ra[mt * 4 + 3] = rv.w * c4;
    }
    float cbv[4];
#pragma unroll
    for (int nt = 0; nt < 4; ++nt) cbv[nt] = sqb[wcol + nt * 16 + ccol] * c4;

    float2 lsum2 = make_float2(0.f, 0.f);
#pragma unroll
    for (int mt = 0; mt < 8; ++mt) {
#pragma unroll
      for (int nt = 0; nt < 4; ++nt) {
        float cb = cbv[nt];
#pragma unroll
        for (int rp = 0; rp < 4; rp += 2) {
          float2 g = make_float2(acc[mt][nt][rp], acc[mt][nt][rp + 1]);
          float2 sab =
              make_float2(ra[mt * 4 + rp] + cb, ra[mt * 4 + rp + 1] + cb);
          float2 u = pk_fma(g, m2v, sab);
          float2 e = make_float2(__builtin_amdgcn_exp2f(u.x),
                                 __builtin_amdgcn_exp2f(u.y));
          float2 e2 = pk_mul(e, e);
          float2 e4 = pk_mul(e2, e2);
          float2 e8 = pk_mul(e4, e4);
          float2 s = pk_add(e, e2);
          s = pk_add(s, e4);
          s = pk_add(s, e8);
          s = pk_fma(e8, e8, s);  // + e^16
          lsum2 = pk_add(lsum2, s);
        }
      }
    }
    float lsum = lsum2.x + lsum2.y;
#pragma unroll
    for (int off = 32; off; off >>= 1) lsum += __shfl_down(lsum, off, 64);
    if (lane == 0) red[w] = lsum;
    __syncthreads();
    if (t == 0) {
      float wsign = ((bi < halfTiles) == (bj < halfTiles)) ? 1.f : -1.f;
      float f = (bi == bj) ? 1.f : 2.f;
      float s = red[0] + red[1] + red[2] + red[3] + red[4] + red[5] + red[6] +
                red[7];
      atomicAdd(out, wsign * f * inv * s);
    }
    __syncthreads();  // red[] + LDS safe for next rep
  }
}

extern "C" void kernel_launch(void* const* d_in, const int* in_sizes, int n_in,
                              void* d_out, int out_size, void* d_ws,
                              size_t ws_size, hipStream_t stream) {
  const float* src = (const float*)d_in[0];
  const float* tgt = (const float*)d_in[1];
  int ns = in_sizes[0] / KDIM;   // 4096
  int ntr = in_sizes[1] / KDIM;  // 4096
  int n = ns + ntr;              // 8192

  char* ws = (char*)d_ws;
  unsigned short* Tbf = (unsigned short*)ws;  // 4 MiB bf16 matrix
  size_t off = (size_t)n * KDIM * sizeof(unsigned short);
  float* sq = (float*)(ws + off);     off += (size_t)n * 4;
  float* scol = (float*)(ws + off);   off += (size_t)KDIM * 4;
  float* sum_sq = (float*)(ws + off);

  // zero scol + sum_sq (ws is poisoned 0xAA before every call)
  hipMemsetAsync(scol, 0, (KDIM + 1) * sizeof(float), stream);

  mmd_stage<<<n / 32, 256, 0, stream>>>(src, tgt, ns, Tbf, sq, scol, sum_sq,
                                        (float*)d_out);

  int nb = n / BT;                 // 32
  int ntiles = nb * (nb + 1) / 2;  // 528
  int grid = 512;
  int extra = ntiles - grid;       // 16 double-duty blocks, dispatched first
  if (extra < 0) { grid = ntiles; extra = 0; }
  int dyn = 4 * TILE_SH * (int)sizeof(short);  // 128 KiB
  hipFuncSetAttribute(reinterpret_cast<const void*>(mmd_main),
                      hipFuncAttributeMaxDynamicSharedMemorySize, dyn);
  mmd_main<<<grid, 512, dyn, stream>>>(Tbf, sq, scol, sum_sq, (float*)d_out, n,
                                       ns / BT, extra,
                                       1.f / ((float)ns * (float)ns));
}